// Round 13
// baseline (894.261 us; speedup 1.0000x reference)
//
#include <hip/hip_runtime.h>

#define H 192
#define NL 5
#define NN 60000
#define NE 120000
#define NG 2048
#define ND 200
#define LDA 392  // 384 + 8 bf16 pad -> 784B row stride (16B aligned)
#define NT 128   // upd nodes per block
#define LDU 200  // 192 + 8 pad (upd tile row stride, shorts)
#define MSGB 512 // persistent msg blocks (2 per CU)

typedef __bf16 bfrag __attribute__((ext_vector_type(8)));
typedef __bf16 bf16x4 __attribute__((ext_vector_type(4)));
typedef float f32x4 __attribute__((ext_vector_type(4)));

__device__ __forceinline__ unsigned short f2bf(float f) {
  union { float f; unsigned u; } v; v.f = f;
  return (unsigned short)((v.u + 0x7FFFu + ((v.u >> 16) & 1u)) >> 16);
}
__device__ __forceinline__ float bflo(unsigned u) {
  union { unsigned u; float f; } v; v.u = u << 16; return v.f;
}
__device__ __forceinline__ float bfhi(unsigned u) {
  union { unsigned u; float f; } v; v.u = u & 0xffff0000u; return v.f;
}
// tanh-approx GELU via exp2 + raw v_rcp_f32 (1 ulp; behind bf16 store).
__device__ __forceinline__ float gelu(float x) {
  const float t = exp2f(x * (-2.3020922f - 0.10293942f * x * x));
  return x * __builtin_amdgcn_rcpf(1.f + t);
}

// ---------------- fold: W2' = W2 . Ua ; v2 = b2 . Ua ----------------
__global__ __launch_bounds__(256) void fold_kernel(
    const float* __restrict__ msg_w2, const float* __restrict__ upd_w,
    const float* __restrict__ msg_b2, float* __restrict__ W2p,
    float* __restrict__ v2) {
  __shared__ float row4[4][192];
  const int bid = blockIdx.x;
  const int l = bid / 97, sub = bid % 97;
  const int j = threadIdx.x;
  if (j < 192) {
    if (sub < 96) {
      const int k0 = sub * 4;
#pragma unroll
      for (int rr = 0; rr < 4; ++rr)
        row4[rr][j] = msg_w2[(size_t)l * 384 * 192 + (size_t)(k0 + rr) * 192 + j];
    } else {
      row4[0][j] = msg_b2[l * 192 + j];
    }
  }
  __syncthreads();
  if (j >= 192) return;
  const float* Ua = upd_w + (size_t)l * 384 * 192 + (size_t)192 * 192;
  float acc[4] = {0.f, 0.f, 0.f, 0.f};
  for (int t = 0; t < 192; ++t) {
    const float u = Ua[t * 192 + j];
#pragma unroll
    for (int rr = 0; rr < 4; ++rr) acc[rr] += row4[rr][t] * u;
  }
  if (sub < 96) {
    const int k0 = sub * 4;
#pragma unroll
    for (int rr = 0; rr < 4; ++rr)
      W2p[(size_t)l * 384 * 192 + (size_t)(k0 + rr) * 192 + j] = acc[rr];
  } else {
    v2[l * 192 + j] = acc[0];
  }
}

// ---------------- weight prep: bf16 + MFMA fragment order ----------------
__global__ __launch_bounds__(256) void prep_kernel(
    const float* __restrict__ msg_w1, const float* __restrict__ W2p,
    const float* __restrict__ upd_w, const float* __restrict__ h1_w,
    const float* __restrict__ h2_w, const float* __restrict__ h3_w,
    unsigned short* __restrict__ W1f, float* __restrict__ w1last,
    unsigned short* __restrict__ W2f, unsigned short* __restrict__ Uxf,
    unsigned short* __restrict__ h1f, unsigned short* __restrict__ h2f,
    unsigned short* __restrict__ h3f) {
  int idx = blockIdx.x * 256 + threadIdx.x;
  const int SW1 = NL * 147456;
  const int S2 = NL * 384;
  const int SW2 = NL * 73728;
  const int SUX = NL * 36864;
  if (idx < SW1) {
    int l = idx / 147456, r = idx % 147456;
    int i = r & 7, lane = (r >> 3) & 63, t = r >> 9;
    int kk = t % 12, jblk = t / 12;
    int j = jblk * 16 + (lane & 15);
    int k = kk * 32 + ((lane >> 4) << 3) + i;
    W1f[idx] = f2bf(msg_w1[(size_t)l * 385 * 384 + (size_t)k * 384 + j]);
    return;
  }
  idx -= SW1;
  if (idx < S2) {
    int l = idx / 384, j = idx % 384;
    w1last[idx] = msg_w1[(size_t)l * 385 * 384 + 384 * 384 + j];
    return;
  }
  idx -= S2;
  if (idx < SW2) {
    int l = idx / 73728, r = idx % 73728;
    int i = r & 7, lane = (r >> 3) & 63, t = r >> 9;
    int kk = t % 12, jblk = t / 12;
    int j = jblk * 16 + (lane & 15);
    int k = kk * 32 + ((lane >> 4) << 3) + i;
    W2f[idx] = f2bf(W2p[(size_t)l * 384 * 192 + (size_t)k * 192 + j]);
    return;
  }
  idx -= SW2;
  if (idx < SUX) {  // Ux: rows 0..191 of upd_w; 12 jblk x 6 kk
    int l = idx / 36864, r = idx % 36864;
    int i = r & 7, lane = (r >> 3) & 63, t = r >> 9;
    int kk = t % 6, jblk = t / 6;
    int j = jblk * 16 + (lane & 15);
    int k = kk * 32 + ((lane >> 4) << 3) + i;
    Uxf[idx] = f2bf(upd_w[(size_t)l * 384 * 192 + (size_t)k * 192 + j]);
    return;
  }
  idx -= SUX;
  if (idx < 73728) {
    int i = idx & 7, lane = (idx >> 3) & 63, t = idx >> 9;
    int kk = t % 12, jblk = t / 12;
    int j = jblk * 16 + (lane & 15);
    int k = kk * 32 + ((lane >> 4) << 3) + i;
    h1f[idx] = f2bf(h1_w[(size_t)k * 192 + j]);
    return;
  }
  idx -= 73728;
  if (idx < 18432) {
    int i = idx & 7, lane = (idx >> 3) & 63, t = idx >> 9;
    int kk = t % 6, jblk = t / 6;
    int j = jblk * 16 + (lane & 15);
    int k = kk * 32 + ((lane >> 4) << 3) + i;
    h2f[idx] = f2bf(h2_w[(size_t)k * 96 + j]);
    return;
  }
  idx -= 18432;
  if (idx < 19968) {
    int i = idx & 7, lane = (idx >> 3) & 63, t = idx >> 9;
    int kk = t % 3, jblk = t / 3;
    int j = jblk * 16 + (lane & 15);
    int k = kk * 32 + ((lane >> 4) << 3) + i;
    h3f[idx] = (j < 200) ? f2bf(h3_w[(size_t)k * 200 + j]) : (unsigned short)0;
    return;
  }
}

// ---------------- encoder (bf16 state only) ----------------
__global__ __launch_bounds__(256) void enc_kernel(
    const float* __restrict__ af, const float* __restrict__ w,
    const float* __restrict__ b, const float* __restrict__ g,
    const float* __restrict__ bb, __bf16* __restrict__ xb) {
  const int node = blockIdx.x * 4 + (threadIdx.x >> 6);
  const int lane = threadIdx.x & 63;
  if (node >= NN) return;
  const float a0 = af[node * 4 + 0], a1 = af[node * 4 + 1];
  const float a2 = af[node * 4 + 2], a3 = af[node * 4 + 3];
  float v[3], s = 0.f, ss = 0.f;
#pragma unroll
  for (int i = 0; i < 3; ++i) {
    const int j = lane + i * 64;
    float o = a0 * w[j] + a1 * w[H + j] + a2 * w[2 * H + j] + a3 * w[3 * H + j] + b[j];
    o = gelu(o);
    v[i] = o; s += o; ss += o * o;
  }
#pragma unroll
  for (int m = 1; m < 64; m <<= 1) { s += __shfl_xor(s, m); ss += __shfl_xor(ss, m); }
  const float mu = s * (1.f / H);
  float var = ss * (1.f / H) - mu * mu;
  const float rstd = rsqrtf(fmaxf(var, 0.f) + 1e-5f);
#pragma unroll
  for (int i = 0; i < 3; ++i) {
    const int j = lane + i * 64;
    xb[(size_t)node * H + j] = (__bf16)((v[i] - mu) * rstd * g[j] + bb[j]);
  }
}

// ---------------- CSR build ----------------
__global__ __launch_bounds__(256) void csr_count(const int* __restrict__ ei,
                                                 int* __restrict__ deg) {
  const int e = blockIdx.x * 256 + threadIdx.x;
  if (e < NE) atomicAdd(&deg[ei[NE + e]], 1);
}

__global__ __launch_bounds__(1024) void csr_scan(const int* __restrict__ deg,
                                                 int* __restrict__ start) {
  __shared__ int wsum[16];
  const int tid = threadIdx.x, lane = tid & 63, wv = tid >> 6;
  int carry = 0;
  for (int base = 0; base < NN; base += 1024) {
    const int i = base + tid;
    int v = (i < NN) ? deg[i] : 0;
    int s = v;
#pragma unroll
    for (int d = 1; d < 64; d <<= 1) {
      int t = __shfl_up(s, d);
      if (lane >= d) s += t;
    }
    if (lane == 63) wsum[wv] = s;
    __syncthreads();
    if (wv == 0) {
      int ws_ = (lane < 16) ? wsum[lane] : 0;
#pragma unroll
      for (int d = 1; d < 16; d <<= 1) {
        int t = __shfl_up(ws_, d);
        if (lane >= d) ws_ += t;
      }
      if (lane < 16) wsum[lane] = ws_;
    }
    __syncthreads();
    const int woff = (wv == 0) ? 0 : wsum[wv - 1];
    if (i < NN) start[i] = carry + woff + s - v;
    carry += wsum[15];
    __syncthreads();
  }
  if (tid == 0) start[NN] = NE;
}

// fill: produce inverse map pos[e] = CSR position p
__global__ __launch_bounds__(256) void csr_fill(const int* __restrict__ ei,
                                                const int* __restrict__ start,
                                                int* __restrict__ cur,
                                                int* __restrict__ pos) {
  const int e = blockIdx.x * 256 + threadIdx.x;
  if (e < NE) {
    const int d = ei[NE + e];
    const int p = start[d] + atomicAdd(&cur[d], 1);
    pos[e] = p;
  }
}

// ---------------- graph segment boundaries ----------------
__global__ __launch_bounds__(256) void gseg_kernel(const int* __restrict__ batch,
                                                   int* __restrict__ gstart,
                                                   int* __restrict__ gend) {
  const int i = blockIdx.x * 256 + threadIdx.x;
  if (i >= NN) return;
  const int b = batch[i];
  if (i == 0 || batch[i - 1] != b) gstart[b] = i;
  if (i == NN - 1 || batch[i + 1] != b) gend[b] = i + 1;
}

// ---------------- fused message MLP: persistent blocks + reg prefetch -----
// 512 blocks grid-stride over 1875 edge-tiles. While computing tile t, the
// gather for tile t+MSGB is in flight into registers; regs dump to LDS after
// GEMM2's last A-read barrier (T14 async-STAGE split).
__global__ __launch_bounds__(512, 4) void msg_kernel(
    const __bf16* __restrict__ xb, const int* __restrict__ ei,
    const float* __restrict__ ea, const int* __restrict__ pos,
    const unsigned short* __restrict__ W1f, const float* __restrict__ w1last,
    const float* __restrict__ b1, const unsigned short* __restrict__ W2f,
    unsigned short* __restrict__ m) {
  __shared__ unsigned short A[64 * LDA];
  __shared__ float eaS[64];
  __shared__ int posS[64];
  const int tid = threadIdx.x;
  const int wave = tid >> 6, lane = tid & 63;
  const int lrow = lane & 15, kgrp = lane >> 4;
  const int sr = tid >> 3, sc = tid & 7;  // staging row / col-slice
  const int NTILES = NE / 64;

  // prologue: stage first tile directly into LDS
  {
    const int tile = blockIdx.x * 64;
    if (tid < 64) { eaS[tid] = ea[tile + tid]; posS[tid] = pos[tile + tid]; }
    const int e = tile + sr;
    const uint4* ps = (const uint4*)(xb + (size_t)ei[e] * H);
    const uint4* pd = (const uint4*)(xb + (size_t)ei[NE + e] * H);
#pragma unroll
    for (int i = 0; i < 3; ++i)
      *(uint4*)(&A[sr * LDA + (sc + 8 * i) * 8]) = ps[sc + 8 * i];
#pragma unroll
    for (int i = 3; i < 6; ++i)
      *(uint4*)(&A[sr * LDA + (sc + 8 * i) * 8]) = pd[sc + 8 * i - 24];
  }
  __syncthreads();

  for (int tile_idx = blockIdx.x; tile_idx < NTILES; tile_idx += MSGB) {
    const int tile = tile_idx * 64;
    const bool has_next = (tile_idx + MSGB) < NTILES;

    // issue next tile's gather into registers (latency hides under compute)
    uint4 pf[6];
    float eaN = 0.f;
    int posN = 0;
    if (has_next) {
      const int t2 = (tile_idx + MSGB) * 64;
      const int e2 = t2 + sr;
      const uint4* ps = (const uint4*)(xb + (size_t)ei[e2] * H);
      const uint4* pd = (const uint4*)(xb + (size_t)ei[NE + e2] * H);
#pragma unroll
      for (int i = 0; i < 3; ++i) pf[i] = ps[sc + 8 * i];
#pragma unroll
      for (int i = 3; i < 6; ++i) pf[i] = pd[sc + 8 * i - 24];
      if (tid < 64) { eaN = ea[t2 + tid]; posN = pos[t2 + tid]; }
    }

    // ---- GEMM1: wave owns 3 j-blocks x all 4 e-blocks ----
    const int jb16 = wave * 3;
    f32x4 acc[3][4];
#pragma unroll
    for (int mf = 0; mf < 3; ++mf)
#pragma unroll
      for (int eb = 0; eb < 4; ++eb)
#pragma unroll
        for (int q = 0; q < 4; ++q) acc[mf][eb][q] = 0.f;

#pragma unroll 2
    for (int kk = 0; kk < 12; ++kk) {
      const int k0 = kk * 32 + kgrp * 8;
      bfrag bF[4];
#pragma unroll
      for (int eb = 0; eb < 4; ++eb)
        bF[eb] = *(const bfrag*)(&A[(eb * 16 + lrow) * LDA + k0]);
#pragma unroll
      for (int mf = 0; mf < 3; ++mf) {
        const bfrag aF = *(const bfrag*)(W1f + ((size_t)((jb16 + mf) * 12 + kk) * 64 + lane) * 8);
#pragma unroll
        for (int eb = 0; eb < 4; ++eb)
          acc[mf][eb] = __builtin_amdgcn_mfma_f32_16x16x32_bf16(aF, bF[eb], acc[mf][eb], 0, 0, 0);
      }
    }
    __syncthreads();  // GEMM1 A reads done

    // ---- epilogue: hiddenT -> A ----
#pragma unroll
    for (int mf = 0; mf < 3; ++mf) {
      const int j0 = (jb16 + mf) * 16 + kgrp * 4;
      const float bi0 = b1[j0], bi1 = b1[j0 + 1], bi2 = b1[j0 + 2], bi3 = b1[j0 + 3];
      const float wl0 = w1last[j0], wl1 = w1last[j0 + 1], wl2 = w1last[j0 + 2], wl3 = w1last[j0 + 3];
#pragma unroll
      for (int eb = 0; eb < 4; ++eb) {
        const int e = eb * 16 + lrow;
        const float eav = eaS[e];
        bf16x4 v;
        v[0] = (__bf16)gelu(acc[mf][eb][0] + bi0 + eav * wl0);
        v[1] = (__bf16)gelu(acc[mf][eb][1] + bi1 + eav * wl1);
        v[2] = (__bf16)gelu(acc[mf][eb][2] + bi2 + eav * wl2);
        v[3] = (__bf16)gelu(acc[mf][eb][3] + bi3 + eav * wl3);
        *(bf16x4*)(&A[e * LDA + j0]) = v;
      }
    }
    __syncthreads();  // hidden visible

    // ---- GEMM2: waves 0-3 own 2 j2-blocks, 4-7 own 1 ----
    const int jcnt2 = (wave < 4) ? 2 : 1;
    const int j2b0 = (wave < 4) ? (wave * 2) : (4 + wave);
    f32x4 acc2[2][4];
#pragma unroll
    for (int a = 0; a < 2; ++a)
#pragma unroll
      for (int eb = 0; eb < 4; ++eb)
#pragma unroll
        for (int q = 0; q < 4; ++q) acc2[a][eb][q] = 0.f;

#pragma unroll 2
    for (int kk = 0; kk < 12; ++kk) {
      const int k0 = kk * 32 + kgrp * 8;
      bfrag bF[4];
#pragma unroll
      for (int eb = 0; eb < 4; ++eb)
        bF[eb] = *(const bfrag*)(&A[(eb * 16 + lrow) * LDA + k0]);
#pragma unroll
      for (int a = 0; a < 2; ++a) {
        if (a < jcnt2) {
          const bfrag aF = *(const bfrag*)(W2f + ((size_t)((j2b0 + a) * 12 + kk) * 64 + lane) * 8);
#pragma unroll
          for (int eb = 0; eb < 4; ++eb)
            acc2[a][eb] = __builtin_amdgcn_mfma_f32_16x16x32_bf16(aF, bF[eb], acc2[a][eb], 0, 0, 0);
        }
      }
    }
#pragma unroll
    for (int a = 0; a < 2; ++a) {
      if (a < jcnt2) {
        const int j0 = (j2b0 + a) * 16 + kgrp * 4;
#pragma unroll
        for (int eb = 0; eb < 4; ++eb) {
          const int e = eb * 16 + lrow;
          bf16x4 v;
          v[0] = (__bf16)acc2[a][eb][0];
          v[1] = (__bf16)acc2[a][eb][1];
          v[2] = (__bf16)acc2[a][eb][2];
          v[3] = (__bf16)acc2[a][eb][3];
          *(bf16x4*)(m + (size_t)posS[e] * H + j0) = v;
        }
      }
    }
    __syncthreads();  // GEMM2 A reads (and posS reads) done

    // ---- dump prefetched next tile from regs to LDS ----
    if (has_next) {
#pragma unroll
      for (int i = 0; i < 6; ++i)
        *(uint4*)(&A[sr * LDA + (sc + 8 * i) * 8]) = pf[i];
      if (tid < 64) { eaS[tid] = eaN; posS[tid] = posN; }
      __syncthreads();  // next tile visible
    }
  }
}

// ---------------- update: x·Ux GEMM + contiguous agg' gather + LN ----------
__global__ __launch_bounds__(512, 4) void upd_kernel(
    const unsigned short* __restrict__ Uxf, const float* __restrict__ ub,
    const float* __restrict__ v2, const float* __restrict__ lng,
    const float* __restrict__ lnb, const unsigned short* __restrict__ m,
    const int* __restrict__ start, __bf16* xb) {
  __shared__ unsigned short A[NT * LDU];
  __shared__ float wsm[8][NT];
  __shared__ float wsq[8][NT];
  __shared__ float mur[NT], rsr[NT];
  __shared__ float degS[NT];
  const int tid = threadIdx.x;
  const int wave = tid >> 6, lane = tid & 63;
  const int lrow = lane & 15, kgrp = lane >> 4;
  const int tile = blockIdx.x * NT;

  const int r = tid >> 2, q4 = tid & 3;
  const int node = tile + r;
  if (node < NN) {
    const uint4* px = (const uint4*)(xb + (size_t)node * H + q4 * 48);
#pragma unroll
    for (int i = 0; i < 6; ++i)
      *(uint4*)(&A[r * LDU + q4 * 48 + i * 8]) = px[i];
  } else {
#pragma unroll
    for (int i = 0; i < 6; ++i)
      *(uint4*)(&A[r * LDU + q4 * 48 + i * 8]) = make_uint4(0, 0, 0, 0);
  }
  __syncthreads();

  const int jcnt = (wave < 4) ? 2 : 1;
  const int jb0 = (wave < 4) ? (wave * 2) : (4 + wave);

  f32x4 acc[2][8];
#pragma unroll
  for (int a = 0; a < 2; ++a)
#pragma unroll
    for (int eb = 0; eb < 8; ++eb)
#pragma unroll
      for (int q = 0; q < 4; ++q) acc[a][eb][q] = 0.f;

#pragma unroll 1
  for (int kk = 0; kk < 6; ++kk) {
    const int k0 = kk * 32 + kgrp * 8;
    bfrag bF[8];
#pragma unroll
    for (int eb = 0; eb < 8; ++eb)
      bF[eb] = *(const bfrag*)(&A[(eb * 16 + lrow) * LDU + k0]);
#pragma unroll
    for (int a = 0; a < 2; ++a) {
      if (a < jcnt) {
        const bfrag aF = *(const bfrag*)(Uxf + ((size_t)((jb0 + a) * 6 + kk) * 64 + lane) * 8);
#pragma unroll
        for (int eb = 0; eb < 8; ++eb)
          acc[a][eb] = __builtin_amdgcn_mfma_f32_16x16x32_bf16(aF, bF[eb], acc[a][eb], 0, 0, 0);
      }
    }
  }
  __syncthreads();  // GEMM reads of A done

  // gather agg' = sum of CONTIGUOUS m rows [start[node], start[node+1])
  if (node < NN) {
    const int p0 = start[node], p1 = start[node + 1];
    if (q4 == 0) degS[r] = (float)(p1 - p0);
#pragma unroll
    for (int hh = 0; hh < 2; ++hh) {
      const int c0 = q4 * 48 + hh * 24;
      float av[24];
#pragma unroll
      for (int i = 0; i < 24; ++i) av[i] = 0.f;
      for (int p = p0; p < p1; ++p) {
        const uint4* mr = (const uint4*)(m + (size_t)p * H + c0);
#pragma unroll
        for (int i = 0; i < 3; ++i) {
          const uint4 u = mr[i];
          av[i * 8 + 0] += bflo(u.x); av[i * 8 + 1] += bfhi(u.x);
          av[i * 8 + 2] += bflo(u.y); av[i * 8 + 3] += bfhi(u.y);
          av[i * 8 + 4] += bflo(u.z); av[i * 8 + 5] += bfhi(u.z);
          av[i * 8 + 6] += bflo(u.w); av[i * 8 + 7] += bfhi(u.w);
        }
      }
#pragma unroll
      for (int i = 0; i < 24; i += 4) {
        bf16x4 v;
        v[0] = (__bf16)av[i]; v[1] = (__bf16)av[i + 1];
        v[2] = (__bf16)av[i + 2]; v[3] = (__bf16)av[i + 3];
        *(bf16x4*)(&A[r * LDU + c0 + i]) = v;
      }
    }
  } else {
    if (q4 == 0) degS[r] = 0.f;
#pragma unroll
    for (int i = 0; i < 48; i += 8)
      *(uint4*)(&A[r * LDU + q4 * 48 + i]) = make_uint4(0, 0, 0, 0);
  }
  __syncthreads();

  // epilogue: v = xb + gelu(xUx + agg' + deg*v2 + ub); LN partials
  float lsum[8], lsq[8];
#pragma unroll
  for (int eb = 0; eb < 8; ++eb) { lsum[eb] = 0.f; lsq[eb] = 0.f; }
#pragma unroll
  for (int a = 0; a < 2; ++a) {
    if (a < jcnt) {
      const int jb = (jb0 + a) * 16 + kgrp * 4;
      const float4 ub4 = *(const float4*)(ub + jb);
      const float4 v24 = *(const float4*)(v2 + jb);
#pragma unroll
      for (int eb = 0; eb < 8; ++eb) {
        const int nc = eb * 16 + lrow;
        const int n2 = tile + nc;
        if (n2 < NN) {
          const bf16x4 ag = *(const bf16x4*)(&A[nc * LDU + jb]);
          const float d = degS[nc];
          const bf16x4 xr = *(const bf16x4*)(xb + (size_t)n2 * H + jb);
          acc[a][eb][0] = (float)xr[0] + gelu(acc[a][eb][0] + (float)ag[0] + d * v24.x + ub4.x);
          acc[a][eb][1] = (float)xr[1] + gelu(acc[a][eb][1] + (float)ag[1] + d * v24.y + ub4.y);
          acc[a][eb][2] = (float)xr[2] + gelu(acc[a][eb][2] + (float)ag[2] + d * v24.z + ub4.z);
          acc[a][eb][3] = (float)xr[3] + gelu(acc[a][eb][3] + (float)ag[3] + d * v24.w + ub4.w);
        } else {
          acc[a][eb][0] = 0.f; acc[a][eb][1] = 0.f;
          acc[a][eb][2] = 0.f; acc[a][eb][3] = 0.f;
        }
#pragma unroll
        for (int q = 0; q < 4; ++q) {
          lsum[eb] += acc[a][eb][q];
          lsq[eb] += acc[a][eb][q] * acc[a][eb][q];
        }
      }
    }
  }
#pragma unroll
  for (int eb = 0; eb < 8; ++eb) {
    lsum[eb] += __shfl_xor(lsum[eb], 16);
    lsum[eb] += __shfl_xor(lsum[eb], 32);
    lsq[eb] += __shfl_xor(lsq[eb], 16);
    lsq[eb] += __shfl_xor(lsq[eb], 32);
  }
  if (kgrp == 0) {
#pragma unroll
    for (int eb = 0; eb < 8; ++eb) {
      wsm[wave][eb * 16 + lrow] = lsum[eb];
      wsq[wave][eb * 16 + lrow] = lsq[eb];
    }
  }
  __syncthreads();
  if (tid < NT) {
    float s = 0.f, sq = 0.f;
#pragma unroll
    for (int w2 = 0; w2 < 8; ++w2) { s += wsm[w2][tid]; sq += wsq[w2][tid]; }
    const float mu = s * (1.f / H);
    float var = sq * (1.f / H) - mu * mu;
    mur[tid] = mu;
    rsr[tid] = rsqrtf(fmaxf(var, 0.f) + 1e-5f);
  }
  __syncthreads();
#pragma unroll
  for (int a = 0; a < 2; ++a) {
    if (a < jcnt) {
      const int jb = (jb0 + a) * 16 + kgrp * 4;
      const float4 g4 = *(const float4*)(lng + jb);
      const float4 b4 = *(const float4*)(lnb + jb);
#pragma unroll
      for (int eb = 0; eb < 8; ++eb) {
        const int nc = eb * 16 + lrow;
        const int n2 = tile + nc;
        if (n2 < NN) {
          const float mu = mur[nc], rs = rsr[nc];
          bf16x4 ob;
          ob[0] = (__bf16)((acc[a][eb][0] - mu) * rs * g4.x + b4.x);
          ob[1] = (__bf16)((acc[a][eb][1] - mu) * rs * g4.y + b4.y);
          ob[2] = (__bf16)((acc[a][eb][2] - mu) * rs * g4.z + b4.z);
          ob[3] = (__bf16)((acc[a][eb][3] - mu) * rs * g4.w + b4.w);
          *(bf16x4*)(xb + (size_t)n2 * H + jb) = ob;
        }
      }
    }
  }
}

// ---------------- pooling: segment mean/max -> Gb[2048][384] bf16 ----------
__global__ __launch_bounds__(256) void pool_kernel(
    const __bf16* __restrict__ xb, const int* __restrict__ gstart,
    const int* __restrict__ gend, __bf16* __restrict__ Gb) {
  const int w = threadIdx.x >> 6, lane = threadIdx.x & 63;
  const int gi = blockIdx.x * 4 + w;
  const int n0 = gstart[gi], n1 = gend[gi];
  float sm[3] = {0.f, 0.f, 0.f};
  float mx[3] = {-INFINITY, -INFINITY, -INFINITY};
  for (int n = n0; n < n1; ++n) {
#pragma unroll
    for (int i = 0; i < 3; ++i) {
      const float v = (float)xb[(size_t)n * H + lane + i * 64];
      sm[i] += v; mx[i] = fmaxf(mx[i], v);
    }
  }
  const int cnt = n1 - n0;
  const float inv = cnt > 0 ? 1.f / (float)cnt : 0.f;
#pragma unroll
  for (int i = 0; i < 3; ++i) {
    const int j = lane + i * 64;
    Gb[(size_t)gi * 384 + j] = (__bf16)(sm[i] * inv);
    Gb[(size_t)gi * 384 + 192 + j] = (__bf16)mx[i];
  }
}

// ---------------- head MLP: 3 MFMA stages, 32 graphs/block ----------------
__global__ __launch_bounds__(512) void head_kernel(
    const __bf16* __restrict__ Gb,
    const unsigned short* __restrict__ h1f, const float* __restrict__ h1b,
    const unsigned short* __restrict__ h2f, const float* __restrict__ h2b,
    const unsigned short* __restrict__ h3f, const float* __restrict__ h3b,
    float* __restrict__ out) {
  __shared__ unsigned short A[32 * LDA];
  const int tid = threadIdx.x;
  const int wave = tid >> 6, lane = tid & 63;
  const int lrow = lane & 15, kgrp = lane >> 4;
  const int tile = blockIdx.x * 32;

  {
    const int r = tid >> 4, s = tid & 15;
    const uint4* pg = (const uint4*)(Gb + (size_t)(tile + r) * 384);
#pragma unroll
    for (int i = 0; i < 3; ++i)
      *(uint4*)(&A[r * LDA + (s + 16 * i) * 8]) = pg[s + 16 * i];
  }
  __syncthreads();

  const int jcnt1 = (wave < 4) ? 2 : 1;
  const int jb1 = (wave < 4) ? (wave * 2) : (4 + wave);
  f32x4 acc[2][2];
#pragma unroll
  for (int a = 0; a < 2; ++a)
#pragma unroll
    for (int eb = 0; eb < 2; ++eb)
#pragma unroll
      for (int q = 0; q < 4; ++q) acc[a][eb][q] = 0.f;
#pragma unroll 2
  for (int kk = 0; kk < 12; ++kk) {
    const int k0 = kk * 32 + kgrp * 8;
    bfrag bF[2];
#pragma unroll
    for (int eb = 0; eb < 2; ++eb)
      bF[eb] = *(const bfrag*)(&A[(eb * 16 + lrow) * LDA + k0]);
#pragma unroll
    for (int a = 0; a < 2; ++a) {
      if (a < jcnt1) {
        const bfrag aF = *(const bfrag*)(h1f + ((size_t)((jb1 + a) * 12 + kk) * 64 + lane) * 8);
#pragma unroll
        for (int eb = 0; eb < 2; ++eb)
          acc[a][eb] = __builtin_amdgcn_mfma_f32_16x16x32_bf16(aF, bF[eb], acc[a][eb], 0, 0, 0);
      }
    }
  }
  __syncthreads();
#pragma unroll
  for (int a = 0; a < 2; ++a) {
    if (a < jcnt1) {
      const int j0 = (jb1 + a) * 16 + kgrp * 4;
      const float4 b4 = *(const float4*)(h1b + j0);
#pragma unroll
      for (int eb = 0; eb < 2; ++eb) {
        const int g = eb * 16 + lrow;
        bf16x4 v;
        v[0] = (__bf16)gelu(acc[a][eb][0] + b4.x);
        v[1] = (__bf16)gelu(acc[a][eb][1] + b4.y);
        v[2] = (__bf16)gelu(acc[a][eb][2] + b4.z);
        v[3] = (__bf16)gelu(acc[a][eb][3] + b4.w);
        *(bf16x4*)(&A[g * LDA + j0]) = v;
      }
    }
  }
  __syncthreads();

  f32x4 acc2[2];
#pragma unroll
  for (int eb = 0; eb < 2; ++eb)
#pragma unroll
    for (int q = 0; q < 4; ++q) acc2[eb][q] = 0.f;
  if (wave < 6) {
#pragma unroll 2
    for (int kk = 0; kk < 6; ++kk) {
      const int k0 = kk * 32 + kgrp * 8;
      bfrag bF[2];
#pragma unroll
      for (int eb = 0; eb < 2; ++eb)
        bF[eb] = *(const bfrag*)(&A[(eb * 16 + lrow) * LDA + k0]);
      const bfrag aF = *(const bfrag*)(h2f + ((size_t)(wave * 6 + kk) * 64 + lane) * 8);
#pragma unroll
      for (int eb = 0; eb < 2; ++eb)
        acc2[eb] = __builtin_amdgcn_mfma_f32_16x16x32_bf16(aF, bF[eb], acc2[eb], 0, 0, 0);
    }
  }
  __syncthreads();
  if (wave < 6) {
    const int j0 = wave * 16 + kgrp * 4;
    const float4 b4 = *(const float4*)(h2b + j0);
#pragma unroll
    for (int eb = 0; eb < 2; ++eb) {
      const int g = eb * 16 + lrow;
      bf16x4 v;
      v[0] = (__bf16)gelu(acc2[eb][0] + b4.x);
      v[1] = (__bf16)gelu(acc2[eb][1] + b4.y);
      v[2] = (__bf16)gelu(acc2[eb][2] + b4.z);
      v[3] = (__bf16)gelu(acc2[eb][3] + b4.w);
      *(bf16x4*)(&A[g * LDA + 192 + j0]) = v;
    }
  }
  __syncthreads();

  const int jcnt3 = (wave < 5) ? 2 : 1;
  const int jb3 = (wave < 5) ? (wave * 2) : (wave + 5);
  f32x4 acc3[2][2];
#pragma unroll
  for (int a = 0; a < 2; ++a)
#pragma unroll
    for (int eb = 0; eb < 2; ++eb)
#pragma unroll
      for (int q = 0; q < 4; ++q) acc3[a][eb][q] = 0.f;
#pragma unroll
  for (int kk = 0; kk < 3; ++kk) {
    const int k0 = 192 + kk * 32 + kgrp * 8;
    bfrag bF[2];
#pragma unroll
    for (int eb = 0; eb < 2; ++eb)
      bF[eb] = *(const bfrag*)(&A[(eb * 16 + lrow) * LDA + k0]);
#pragma unroll
    for (int a = 0; a < 2; ++a) {
      if (a < jcnt3) {
        const bfrag aF = *(const bfrag*)(h3f + ((size_t)((jb3 + a) * 3 + kk) * 64 + lane) * 8);
#pragma unroll
        for (int eb = 0; eb < 2; ++eb)
          acc3[a][eb] = __builtin_amdgcn_mfma_f32_16x16x32_bf16(aF, bF[eb], acc3[a][eb], 0, 0, 0);
      }
    }
  }
#pragma unroll
  for (int a = 0; a < 2; ++a) {
    if (a < jcnt3) {
      const int jb = jb3 + a;
      const int j0 = jb * 16 + kgrp * 4;
#pragma unroll
      for (int eb = 0; eb < 2; ++eb) {
        const int g = tile + eb * 16 + lrow;
        if (jb < 12) {
          const float4 b4 = *(const float4*)(h3b + j0);
          float4 o;
          o.x = acc3[a][eb][0] + b4.x;
          o.y = acc3[a][eb][1] + b4.y;
          o.z = acc3[a][eb][2] + b4.z;
          o.w = acc3[a][eb][3] + b4.w;
          *(float4*)(out + (size_t)g * ND + j0) = o;
        } else {
#pragma unroll
          for (int t = 0; t < 4; ++t) {
            const int j = j0 + t;
            if (j < ND) out[(size_t)g * ND + j] = acc3[a][eb][t] + h3b[j];
          }
        }
      }
    }
  }
}

extern "C" void kernel_launch(void* const* d_in, const int* in_sizes, int n_in,
                              void* d_out, int out_size, void* d_ws, size_t ws_size,
                              hipStream_t stream) {
  const float* atom   = (const float*)d_in[0];
  const float* ea     = (const float*)d_in[1];
  const int*   ei     = (const int*)d_in[2];
  const int*   batch  = (const int*)d_in[3];
  const float* enc_w  = (const float*)d_in[4];
  const float* enc_b  = (const float*)d_in[5];
  const float* enc_lng= (const float*)d_in[6];
  const float* enc_lnb= (const float*)d_in[7];
  const float* msg_w1 = (const float*)d_in[8];
  const float* msg_b1 = (const float*)d_in[9];
  const float* msg_w2 = (const float*)d_in[10];
  const float* msg_b2 = (const float*)d_in[11];
  const float* upd_w  = (const float*)d_in[12];
  const float* upd_b  = (const float*)d_in[13];
  const float* ln_g   = (const float*)d_in[14];
  const float* ln_b   = (const float*)d_in[15];
  const float* h1_w   = (const float*)d_in[16];
  const float* h1_b   = (const float*)d_in[17];
  const float* h2_w   = (const float*)d_in[18];
  const float* h2_b   = (const float*)d_in[19];
  const float* h3_w   = (const float*)d_in[20];
  const float* h3_b   = (const float*)d_in[21];
  float* out = (float*)d_out;

  char* ws = (char*)d_ws;
  size_t off = 0;
  auto alloc = [&](size_t bytes) -> void* {
    void* p = ws + off;
    off = (off + bytes + 255) & ~(size_t)255;
    return p;
  };
  __bf16* xb          = (__bf16*)alloc((size_t)NN * H * 2);
  unsigned short* msg = (unsigned short*)alloc((size_t)NE * H * 2);
  unsigned short* W1f = (unsigned short*)alloc((size_t)NL * 147456 * 2);
  float* w1last       = (float*)alloc((size_t)NL * 384 * 4);
  unsigned short* W2f = (unsigned short*)alloc((size_t)NL * 73728 * 2);
  unsigned short* Uxf = (unsigned short*)alloc((size_t)NL * 36864 * 2);
  float* W2p          = (float*)alloc((size_t)NL * 384 * 192 * 4);
  float* v2           = (float*)alloc((size_t)NL * 192 * 4);
  unsigned short* h1f = (unsigned short*)alloc((size_t)73728 * 2);
  unsigned short* h2f = (unsigned short*)alloc((size_t)18432 * 2);
  unsigned short* h3f = (unsigned short*)alloc((size_t)19968 * 2);
  __bf16* Gb          = (__bf16*)alloc((size_t)NG * 384 * 2);
  int* deg            = (int*)alloc((size_t)NN * 4);
  int* cstart         = (int*)alloc((size_t)(NN + 1) * 4);
  int* pos            = (int*)alloc((size_t)NE * 4);
  int* gstart         = (int*)alloc((size_t)NG * 4);
  int* gend           = (int*)alloc((size_t)NG * 4);

  fold_kernel<<<NL * 97, 256, 0, stream>>>(msg_w2, upd_w, msg_b2, W2p, v2);
  prep_kernel<<<5486, 256, 0, stream>>>(msg_w1, W2p, upd_w, h1_w, h2_w, h3_w,
                                        W1f, w1last, W2f, Uxf, h1f, h2f, h3f);
  enc_kernel<<<NN / 4, 256, 0, stream>>>(atom, enc_w, enc_b, enc_lng, enc_lnb, xb);

  hipMemsetAsync(deg, 0, (size_t)NN * 4, stream);
  csr_count<<<(NE + 255) / 256, 256, 0, stream>>>(ei, deg);
  csr_scan<<<1, 1024, 0, stream>>>(deg, cstart);
  hipMemsetAsync(deg, 0, (size_t)NN * 4, stream);
  csr_fill<<<(NE + 255) / 256, 256, 0, stream>>>(ei, cstart, deg, pos);

  hipMemsetAsync(gstart, 0, (size_t)NG * 4, stream);
  hipMemsetAsync(gend, 0, (size_t)NG * 4, stream);
  gseg_kernel<<<(NN + 255) / 256, 256, 0, stream>>>(batch, gstart, gend);

  for (int l = 0; l < NL; ++l) {
    msg_kernel<<<MSGB, 512, 0, stream>>>(
        xb, ei, ea, pos, W1f + (size_t)l * 147456, w1last + l * 384,
        msg_b1 + l * 384, W2f + (size_t)l * 73728, msg);
    upd_kernel<<<(NN + NT - 1) / NT, 512, 0, stream>>>(
        Uxf + (size_t)l * 36864, upd_b + l * 192, v2 + l * 192,
        ln_g + l * 192, ln_b + l * 192, msg, cstart, xb);
  }
  pool_kernel<<<NG / 4, 256, 0, stream>>>(xb, gstart, gend, Gb);
  head_kernel<<<NG / 32, 512, 0, stream>>>(Gb, h1f, h1_b, h2f, h2_b, h3f, h3_b, out);
}

// Round 14
// 755.899 us; speedup vs baseline: 1.1830x; 1.1830x over previous
//
#include <hip/hip_runtime.h>

#define H 192
#define NL 5
#define NN 60000
#define NE 120000
#define NG 2048
#define ND 200
#define LDA 392  // 384 + 8 bf16 pad -> 784B row stride (16B aligned)
#define NT 128   // upd nodes per block
#define LDU 200  // 192 + 8 pad (upd tile row stride, shorts)

typedef __bf16 bfrag __attribute__((ext_vector_type(8)));
typedef __bf16 bf16x4 __attribute__((ext_vector_type(4)));
typedef float f32x4 __attribute__((ext_vector_type(4)));

__device__ __forceinline__ unsigned short f2bf(float f) {
  union { float f; unsigned u; } v; v.f = f;
  return (unsigned short)((v.u + 0x7FFFu + ((v.u >> 16) & 1u)) >> 16);
}
__device__ __forceinline__ float bflo(unsigned u) {
  union { unsigned u; float f; } v; v.u = u << 16; return v.f;
}
__device__ __forceinline__ float bfhi(unsigned u) {
  union { unsigned u; float f; } v; v.u = u & 0xffff0000u; return v.f;
}
// tanh-approx GELU via exp2 + raw v_rcp_f32 (1 ulp; behind bf16 store).
__device__ __forceinline__ float gelu(float x) {
  const float t = exp2f(x * (-2.3020922f - 0.10293942f * x * x));
  return x * __builtin_amdgcn_rcpf(1.f + t);
}

// ---------------- fold: W2' = W2 . Ua ; v2 = b2 . Ua ----------------
__global__ __launch_bounds__(256) void fold_kernel(
    const float* __restrict__ msg_w2, const float* __restrict__ upd_w,
    const float* __restrict__ msg_b2, float* __restrict__ W2p,
    float* __restrict__ v2) {
  __shared__ float row4[4][192];
  const int bid = blockIdx.x;
  const int l = bid / 97, sub = bid % 97;
  const int j = threadIdx.x;
  if (j < 192) {
    if (sub < 96) {
      const int k0 = sub * 4;
#pragma unroll
      for (int rr = 0; rr < 4; ++rr)
        row4[rr][j] = msg_w2[(size_t)l * 384 * 192 + (size_t)(k0 + rr) * 192 + j];
    } else {
      row4[0][j] = msg_b2[l * 192 + j];
    }
  }
  __syncthreads();
  if (j >= 192) return;
  const float* Ua = upd_w + (size_t)l * 384 * 192 + (size_t)192 * 192;
  float acc[4] = {0.f, 0.f, 0.f, 0.f};
  for (int t = 0; t < 192; ++t) {
    const float u = Ua[t * 192 + j];
#pragma unroll
    for (int rr = 0; rr < 4; ++rr) acc[rr] += row4[rr][t] * u;
  }
  if (sub < 96) {
    const int k0 = sub * 4;
#pragma unroll
    for (int rr = 0; rr < 4; ++rr)
      W2p[(size_t)l * 384 * 192 + (size_t)(k0 + rr) * 192 + j] = acc[rr];
  } else {
    v2[l * 192 + j] = acc[0];
  }
}

// ---------------- weight prep: bf16 + MFMA fragment order ----------------
__global__ __launch_bounds__(256) void prep_kernel(
    const float* __restrict__ msg_w1, const float* __restrict__ W2p,
    const float* __restrict__ upd_w, const float* __restrict__ h1_w,
    const float* __restrict__ h2_w, const float* __restrict__ h3_w,
    unsigned short* __restrict__ W1f, float* __restrict__ w1last,
    unsigned short* __restrict__ W2f, unsigned short* __restrict__ Uxf,
    unsigned short* __restrict__ h1f, unsigned short* __restrict__ h2f,
    unsigned short* __restrict__ h3f) {
  int idx = blockIdx.x * 256 + threadIdx.x;
  const int SW1 = NL * 147456;
  const int S2 = NL * 384;
  const int SW2 = NL * 73728;
  const int SUX = NL * 36864;
  if (idx < SW1) {
    int l = idx / 147456, r = idx % 147456;
    int i = r & 7, lane = (r >> 3) & 63, t = r >> 9;
    int kk = t % 12, jblk = t / 12;
    int j = jblk * 16 + (lane & 15);
    int k = kk * 32 + ((lane >> 4) << 3) + i;
    W1f[idx] = f2bf(msg_w1[(size_t)l * 385 * 384 + (size_t)k * 384 + j]);
    return;
  }
  idx -= SW1;
  if (idx < S2) {
    int l = idx / 384, j = idx % 384;
    w1last[idx] = msg_w1[(size_t)l * 385 * 384 + 384 * 384 + j];
    return;
  }
  idx -= S2;
  if (idx < SW2) {
    int l = idx / 73728, r = idx % 73728;
    int i = r & 7, lane = (r >> 3) & 63, t = r >> 9;
    int kk = t % 12, jblk = t / 12;
    int j = jblk * 16 + (lane & 15);
    int k = kk * 32 + ((lane >> 4) << 3) + i;
    W2f[idx] = f2bf(W2p[(size_t)l * 384 * 192 + (size_t)k * 192 + j]);
    return;
  }
  idx -= SW2;
  if (idx < SUX) {  // Ux: rows 0..191 of upd_w; 12 jblk x 6 kk
    int l = idx / 36864, r = idx % 36864;
    int i = r & 7, lane = (r >> 3) & 63, t = r >> 9;
    int kk = t % 6, jblk = t / 6;
    int j = jblk * 16 + (lane & 15);
    int k = kk * 32 + ((lane >> 4) << 3) + i;
    Uxf[idx] = f2bf(upd_w[(size_t)l * 384 * 192 + (size_t)k * 192 + j]);
    return;
  }
  idx -= SUX;
  if (idx < 73728) {
    int i = idx & 7, lane = (idx >> 3) & 63, t = idx >> 9;
    int kk = t % 12, jblk = t / 12;
    int j = jblk * 16 + (lane & 15);
    int k = kk * 32 + ((lane >> 4) << 3) + i;
    h1f[idx] = f2bf(h1_w[(size_t)k * 192 + j]);
    return;
  }
  idx -= 73728;
  if (idx < 18432) {
    int i = idx & 7, lane = (idx >> 3) & 63, t = idx >> 9;
    int kk = t % 6, jblk = t / 6;
    int j = jblk * 16 + (lane & 15);
    int k = kk * 32 + ((lane >> 4) << 3) + i;
    h2f[idx] = f2bf(h2_w[(size_t)k * 96 + j]);
    return;
  }
  idx -= 18432;
  if (idx < 19968) {
    int i = idx & 7, lane = (idx >> 3) & 63, t = idx >> 9;
    int kk = t % 3, jblk = t / 3;
    int j = jblk * 16 + (lane & 15);
    int k = kk * 32 + ((lane >> 4) << 3) + i;
    h3f[idx] = (j < 200) ? f2bf(h3_w[(size_t)k * 200 + j]) : (unsigned short)0;
    return;
  }
}

// ---------------- encoder (bf16 state only) ----------------
__global__ __launch_bounds__(256) void enc_kernel(
    const float* __restrict__ af, const float* __restrict__ w,
    const float* __restrict__ b, const float* __restrict__ g,
    const float* __restrict__ bb, __bf16* __restrict__ xb) {
  const int node = blockIdx.x * 4 + (threadIdx.x >> 6);
  const int lane = threadIdx.x & 63;
  if (node >= NN) return;
  const float a0 = af[node * 4 + 0], a1 = af[node * 4 + 1];
  const float a2 = af[node * 4 + 2], a3 = af[node * 4 + 3];
  float v[3], s = 0.f, ss = 0.f;
#pragma unroll
  for (int i = 0; i < 3; ++i) {
    const int j = lane + i * 64;
    float o = a0 * w[j] + a1 * w[H + j] + a2 * w[2 * H + j] + a3 * w[3 * H + j] + b[j];
    o = gelu(o);
    v[i] = o; s += o; ss += o * o;
  }
#pragma unroll
  for (int m = 1; m < 64; m <<= 1) { s += __shfl_xor(s, m); ss += __shfl_xor(ss, m); }
  const float mu = s * (1.f / H);
  float var = ss * (1.f / H) - mu * mu;
  const float rstd = rsqrtf(fmaxf(var, 0.f) + 1e-5f);
#pragma unroll
  for (int i = 0; i < 3; ++i) {
    const int j = lane + i * 64;
    xb[(size_t)node * H + j] = (__bf16)((v[i] - mu) * rstd * g[j] + bb[j]);
  }
}

// ---------------- CSR build ----------------
__global__ __launch_bounds__(256) void csr_count(const int* __restrict__ ei,
                                                 int* __restrict__ deg) {
  const int e = blockIdx.x * 256 + threadIdx.x;
  if (e < NE) atomicAdd(&deg[ei[NE + e]], 1);
}

__global__ __launch_bounds__(1024) void csr_scan(const int* __restrict__ deg,
                                                 int* __restrict__ start) {
  __shared__ int wsum[16];
  const int tid = threadIdx.x, lane = tid & 63, wv = tid >> 6;
  int carry = 0;
  for (int base = 0; base < NN; base += 1024) {
    const int i = base + tid;
    int v = (i < NN) ? deg[i] : 0;
    int s = v;
#pragma unroll
    for (int d = 1; d < 64; d <<= 1) {
      int t = __shfl_up(s, d);
      if (lane >= d) s += t;
    }
    if (lane == 63) wsum[wv] = s;
    __syncthreads();
    if (wv == 0) {
      int ws_ = (lane < 16) ? wsum[lane] : 0;
#pragma unroll
      for (int d = 1; d < 16; d <<= 1) {
        int t = __shfl_up(ws_, d);
        if (lane >= d) ws_ += t;
      }
      if (lane < 16) wsum[lane] = ws_;
    }
    __syncthreads();
    const int woff = (wv == 0) ? 0 : wsum[wv - 1];
    if (i < NN) start[i] = carry + woff + s - v;
    carry += wsum[15];
    __syncthreads();
  }
  if (tid == 0) start[NN] = NE;
}

// fill: produce inverse map pos[e] = CSR position p
__global__ __launch_bounds__(256) void csr_fill(const int* __restrict__ ei,
                                                const int* __restrict__ start,
                                                int* __restrict__ cur,
                                                int* __restrict__ pos) {
  const int e = blockIdx.x * 256 + threadIdx.x;
  if (e < NE) {
    const int d = ei[NE + e];
    const int p = start[d] + atomicAdd(&cur[d], 1);
    pos[e] = p;
  }
}

// ---------------- graph segment boundaries ----------------
__global__ __launch_bounds__(256) void gseg_kernel(const int* __restrict__ batch,
                                                   int* __restrict__ gstart,
                                                   int* __restrict__ gend) {
  const int i = blockIdx.x * 256 + threadIdx.x;
  if (i >= NN) return;
  const int b = batch[i];
  if (i == 0 || batch[i - 1] != b) gstart[b] = i;
  if (i == NN - 1 || batch[i + 1] != b) gend[b] = i + 1;
}

// ---------------- fused message MLP; m' rows written at CSR position ------
__global__ __launch_bounds__(512, 4) void msg_kernel(
    const __bf16* __restrict__ xb, const int* __restrict__ ei,
    const float* __restrict__ ea, const int* __restrict__ pos,
    const unsigned short* __restrict__ W1f, const float* __restrict__ w1last,
    const float* __restrict__ b1, const unsigned short* __restrict__ W2f,
    unsigned short* __restrict__ m) {
  __shared__ unsigned short A[64 * LDA];
  __shared__ float eaS[64];
  __shared__ int posS[64];
  const int tid = threadIdx.x;
  const int wave = tid >> 6, lane = tid & 63;
  const int lrow = lane & 15, kgrp = lane >> 4;
  const int tile = blockIdx.x * 64;

  if (tid < 64) {
    eaS[tid] = ea[tile + tid];
    posS[tid] = pos[tile + tid];
  }
  {
    const int r = tid >> 3, s = tid & 7;
    const int e = tile + r;
    const uint4* ps = (const uint4*)(xb + (size_t)ei[e] * H);
    const uint4* pd = (const uint4*)(xb + (size_t)ei[NE + e] * H);
#pragma unroll
    for (int i = 0; i < 3; ++i)
      *(uint4*)(&A[r * LDA + (s + 8 * i) * 8]) = ps[s + 8 * i];
#pragma unroll
    for (int i = 3; i < 6; ++i)
      *(uint4*)(&A[r * LDA + (s + 8 * i) * 8]) = pd[s + 8 * i - 24];
  }
  __syncthreads();

  const int jb16 = wave * 3;
  f32x4 acc[3][4];
#pragma unroll
  for (int mf = 0; mf < 3; ++mf)
#pragma unroll
    for (int eb = 0; eb < 4; ++eb)
#pragma unroll
      for (int q = 0; q < 4; ++q) acc[mf][eb][q] = 0.f;

#pragma unroll 2
  for (int kk = 0; kk < 12; ++kk) {
    const int k0 = kk * 32 + kgrp * 8;
    bfrag bF[4];
#pragma unroll
    for (int eb = 0; eb < 4; ++eb)
      bF[eb] = *(const bfrag*)(&A[(eb * 16 + lrow) * LDA + k0]);
#pragma unroll
    for (int mf = 0; mf < 3; ++mf) {
      const bfrag aF = *(const bfrag*)(W1f + ((size_t)((jb16 + mf) * 12 + kk) * 64 + lane) * 8);
#pragma unroll
      for (int eb = 0; eb < 4; ++eb)
        acc[mf][eb] = __builtin_amdgcn_mfma_f32_16x16x32_bf16(aF, bF[eb], acc[mf][eb], 0, 0, 0);
    }
  }
  __syncthreads();

#pragma unroll
  for (int mf = 0; mf < 3; ++mf) {
    const int j0 = (jb16 + mf) * 16 + kgrp * 4;
    const float bi0 = b1[j0], bi1 = b1[j0 + 1], bi2 = b1[j0 + 2], bi3 = b1[j0 + 3];
    const float wl0 = w1last[j0], wl1 = w1last[j0 + 1], wl2 = w1last[j0 + 2], wl3 = w1last[j0 + 3];
#pragma unroll
    for (int eb = 0; eb < 4; ++eb) {
      const int e = eb * 16 + lrow;
      const float eav = eaS[e];
      bf16x4 v;
      v[0] = (__bf16)gelu(acc[mf][eb][0] + bi0 + eav * wl0);
      v[1] = (__bf16)gelu(acc[mf][eb][1] + bi1 + eav * wl1);
      v[2] = (__bf16)gelu(acc[mf][eb][2] + bi2 + eav * wl2);
      v[3] = (__bf16)gelu(acc[mf][eb][3] + bi3 + eav * wl3);
      *(bf16x4*)(&A[e * LDA + j0]) = v;
    }
  }
  __syncthreads();

  const int jcnt2 = (wave < 4) ? 2 : 1;
  const int j2b0 = (wave < 4) ? (wave * 2) : (4 + wave);
  f32x4 acc2[2][4];
#pragma unroll
  for (int a = 0; a < 2; ++a)
#pragma unroll
    for (int eb = 0; eb < 4; ++eb)
#pragma unroll
      for (int q = 0; q < 4; ++q) acc2[a][eb][q] = 0.f;

#pragma unroll 2
  for (int kk = 0; kk < 12; ++kk) {
    const int k0 = kk * 32 + kgrp * 8;
    bfrag bF[4];
#pragma unroll
    for (int eb = 0; eb < 4; ++eb)
      bF[eb] = *(const bfrag*)(&A[(eb * 16 + lrow) * LDA + k0]);
#pragma unroll
    for (int a = 0; a < 2; ++a) {
      if (a < jcnt2) {
        const bfrag aF = *(const bfrag*)(W2f + ((size_t)((j2b0 + a) * 12 + kk) * 64 + lane) * 8);
#pragma unroll
        for (int eb = 0; eb < 4; ++eb)
          acc2[a][eb] = __builtin_amdgcn_mfma_f32_16x16x32_bf16(aF, bF[eb], acc2[a][eb], 0, 0, 0);
      }
    }
  }
#pragma unroll
  for (int a = 0; a < 2; ++a) {
    if (a < jcnt2) {
      const int j0 = (j2b0 + a) * 16 + kgrp * 4;
#pragma unroll
      for (int eb = 0; eb < 4; ++eb) {
        const int e = eb * 16 + lrow;
        bf16x4 v;
        v[0] = (__bf16)acc2[a][eb][0];
        v[1] = (__bf16)acc2[a][eb][1];
        v[2] = (__bf16)acc2[a][eb][2];
        v[3] = (__bf16)acc2[a][eb][3];
        *(bf16x4*)(m + (size_t)posS[e] * H + j0) = v;
      }
    }
  }
}

// ---------------- update: x·Ux GEMM + contiguous agg' gather + LN ----------
__global__ __launch_bounds__(512, 4) void upd_kernel(
    const unsigned short* __restrict__ Uxf, const float* __restrict__ ub,
    const float* __restrict__ v2, const float* __restrict__ lng,
    const float* __restrict__ lnb, const unsigned short* __restrict__ m,
    const int* __restrict__ start, __bf16* xb) {
  __shared__ unsigned short A[NT * LDU];
  __shared__ float wsm[8][NT];
  __shared__ float wsq[8][NT];
  __shared__ float mur[NT], rsr[NT];
  __shared__ float degS[NT];
  const int tid = threadIdx.x;
  const int wave = tid >> 6, lane = tid & 63;
  const int lrow = lane & 15, kgrp = lane >> 4;
  const int tile = blockIdx.x * NT;

  const int r = tid >> 2, q4 = tid & 3;
  const int node = tile + r;
  if (node < NN) {
    const uint4* px = (const uint4*)(xb + (size_t)node * H + q4 * 48);
#pragma unroll
    for (int i = 0; i < 6; ++i)
      *(uint4*)(&A[r * LDU + q4 * 48 + i * 8]) = px[i];
  } else {
#pragma unroll
    for (int i = 0; i < 6; ++i)
      *(uint4*)(&A[r * LDU + q4 * 48 + i * 8]) = make_uint4(0, 0, 0, 0);
  }
  __syncthreads();

  const int jcnt = (wave < 4) ? 2 : 1;
  const int jb0 = (wave < 4) ? (wave * 2) : (4 + wave);

  f32x4 acc[2][8];
#pragma unroll
  for (int a = 0; a < 2; ++a)
#pragma unroll
    for (int eb = 0; eb < 8; ++eb)
#pragma unroll
      for (int q = 0; q < 4; ++q) acc[a][eb][q] = 0.f;

#pragma unroll 1
  for (int kk = 0; kk < 6; ++kk) {
    const int k0 = kk * 32 + kgrp * 8;
    bfrag bF[8];
#pragma unroll
    for (int eb = 0; eb < 8; ++eb)
      bF[eb] = *(const bfrag*)(&A[(eb * 16 + lrow) * LDU + k0]);
#pragma unroll
    for (int a = 0; a < 2; ++a) {
      if (a < jcnt) {
        const bfrag aF = *(const bfrag*)(Uxf + ((size_t)((jb0 + a) * 6 + kk) * 64 + lane) * 8);
#pragma unroll
        for (int eb = 0; eb < 8; ++eb)
          acc[a][eb] = __builtin_amdgcn_mfma_f32_16x16x32_bf16(aF, bF[eb], acc[a][eb], 0, 0, 0);
      }
    }
  }
  __syncthreads();  // GEMM reads of A done

  // gather agg' = sum of CONTIGUOUS m rows [start[node], start[node+1])
  if (node < NN) {
    const int p0 = start[node], p1 = start[node + 1];
    if (q4 == 0) degS[r] = (float)(p1 - p0);
#pragma unroll
    for (int hh = 0; hh < 2; ++hh) {
      const int c0 = q4 * 48 + hh * 24;
      float av[24];
#pragma unroll
      for (int i = 0; i < 24; ++i) av[i] = 0.f;
      for (int p = p0; p < p1; ++p) {
        const uint4* mr = (const uint4*)(m + (size_t)p * H + c0);
#pragma unroll
        for (int i = 0; i < 3; ++i) {
          const uint4 u = mr[i];
          av[i * 8 + 0] += bflo(u.x); av[i * 8 + 1] += bfhi(u.x);
          av[i * 8 + 2] += bflo(u.y); av[i * 8 + 3] += bfhi(u.y);
          av[i * 8 + 4] += bflo(u.z); av[i * 8 + 5] += bfhi(u.z);
          av[i * 8 + 6] += bflo(u.w); av[i * 8 + 7] += bfhi(u.w);
        }
      }
#pragma unroll
      for (int i = 0; i < 24; i += 4) {
        bf16x4 v;
        v[0] = (__bf16)av[i]; v[1] = (__bf16)av[i + 1];
        v[2] = (__bf16)av[i + 2]; v[3] = (__bf16)av[i + 3];
        *(bf16x4*)(&A[r * LDU + c0 + i]) = v;
      }
    }
  } else {
    if (q4 == 0) degS[r] = 0.f;
#pragma unroll
    for (int i = 0; i < 48; i += 8)
      *(uint4*)(&A[r * LDU + q4 * 48 + i]) = make_uint4(0, 0, 0, 0);
  }
  __syncthreads();

  // epilogue: v = xb + gelu(xUx + agg' + deg*v2 + ub); LN partials
  float lsum[8], lsq[8];
#pragma unroll
  for (int eb = 0; eb < 8; ++eb) { lsum[eb] = 0.f; lsq[eb] = 0.f; }
#pragma unroll
  for (int a = 0; a < 2; ++a) {
    if (a < jcnt) {
      const int jb = (jb0 + a) * 16 + kgrp * 4;
      const float4 ub4 = *(const float4*)(ub + jb);
      const float4 v24 = *(const float4*)(v2 + jb);
#pragma unroll
      for (int eb = 0; eb < 8; ++eb) {
        const int nc = eb * 16 + lrow;
        const int n2 = tile + nc;
        if (n2 < NN) {
          const bf16x4 ag = *(const bf16x4*)(&A[nc * LDU + jb]);
          const float d = degS[nc];
          const bf16x4 xr = *(const bf16x4*)(xb + (size_t)n2 * H + jb);
          acc[a][eb][0] = (float)xr[0] + gelu(acc[a][eb][0] + (float)ag[0] + d * v24.x + ub4.x);
          acc[a][eb][1] = (float)xr[1] + gelu(acc[a][eb][1] + (float)ag[1] + d * v24.y + ub4.y);
          acc[a][eb][2] = (float)xr[2] + gelu(acc[a][eb][2] + (float)ag[2] + d * v24.z + ub4.z);
          acc[a][eb][3] = (float)xr[3] + gelu(acc[a][eb][3] + (float)ag[3] + d * v24.w + ub4.w);
        } else {
          acc[a][eb][0] = 0.f; acc[a][eb][1] = 0.f;
          acc[a][eb][2] = 0.f; acc[a][eb][3] = 0.f;
        }
#pragma unroll
        for (int q = 0; q < 4; ++q) {
          lsum[eb] += acc[a][eb][q];
          lsq[eb] += acc[a][eb][q] * acc[a][eb][q];
        }
      }
    }
  }
#pragma unroll
  for (int eb = 0; eb < 8; ++eb) {
    lsum[eb] += __shfl_xor(lsum[eb], 16);
    lsum[eb] += __shfl_xor(lsum[eb], 32);
    lsq[eb] += __shfl_xor(lsq[eb], 16);
    lsq[eb] += __shfl_xor(lsq[eb], 32);
  }
  if (kgrp == 0) {
#pragma unroll
    for (int eb = 0; eb < 8; ++eb) {
      wsm[wave][eb * 16 + lrow] = lsum[eb];
      wsq[wave][eb * 16 + lrow] = lsq[eb];
    }
  }
  __syncthreads();
  if (tid < NT) {
    float s = 0.f, sq = 0.f;
#pragma unroll
    for (int w2 = 0; w2 < 8; ++w2) { s += wsm[w2][tid]; sq += wsq[w2][tid]; }
    const float mu = s * (1.f / H);
    float var = sq * (1.f / H) - mu * mu;
    mur[tid] = mu;
    rsr[tid] = rsqrtf(fmaxf(var, 0.f) + 1e-5f);
  }
  __syncthreads();
#pragma unroll
  for (int a = 0; a < 2; ++a) {
    if (a < jcnt) {
      const int jb = (jb0 + a) * 16 + kgrp * 4;
      const float4 g4 = *(const float4*)(lng + jb);
      const float4 b4 = *(const float4*)(lnb + jb);
#pragma unroll
      for (int eb = 0; eb < 8; ++eb) {
        const int nc = eb * 16 + lrow;
        const int n2 = tile + nc;
        if (n2 < NN) {
          const float mu = mur[nc], rs = rsr[nc];
          bf16x4 ob;
          ob[0] = (__bf16)((acc[a][eb][0] - mu) * rs * g4.x + b4.x);
          ob[1] = (__bf16)((acc[a][eb][1] - mu) * rs * g4.y + b4.y);
          ob[2] = (__bf16)((acc[a][eb][2] - mu) * rs * g4.z + b4.z);
          ob[3] = (__bf16)((acc[a][eb][3] - mu) * rs * g4.w + b4.w);
          *(bf16x4*)(xb + (size_t)n2 * H + jb) = ob;
        }
      }
    }
  }
}

// ---------------- pooling: segment mean/max -> Gb[2048][384] bf16 ----------
__global__ __launch_bounds__(256) void pool_kernel(
    const __bf16* __restrict__ xb, const int* __restrict__ gstart,
    const int* __restrict__ gend, __bf16* __restrict__ Gb) {
  const int w = threadIdx.x >> 6, lane = threadIdx.x & 63;
  const int gi = blockIdx.x * 4 + w;
  const int n0 = gstart[gi], n1 = gend[gi];
  float sm[3] = {0.f, 0.f, 0.f};
  float mx[3] = {-INFINITY, -INFINITY, -INFINITY};
  for (int n = n0; n < n1; ++n) {
#pragma unroll
    for (int i = 0; i < 3; ++i) {
      const float v = (float)xb[(size_t)n * H + lane + i * 64];
      sm[i] += v; mx[i] = fmaxf(mx[i], v);
    }
  }
  const int cnt = n1 - n0;
  const float inv = cnt > 0 ? 1.f / (float)cnt : 0.f;
#pragma unroll
  for (int i = 0; i < 3; ++i) {
    const int j = lane + i * 64;
    Gb[(size_t)gi * 384 + j] = (__bf16)(sm[i] * inv);
    Gb[(size_t)gi * 384 + 192 + j] = (__bf16)mx[i];
  }
}

// ---------------- head MLP: 3 MFMA stages, 32 graphs/block ----------------
__global__ __launch_bounds__(512) void head_kernel(
    const __bf16* __restrict__ Gb,
    const unsigned short* __restrict__ h1f, const float* __restrict__ h1b,
    const unsigned short* __restrict__ h2f, const float* __restrict__ h2b,
    const unsigned short* __restrict__ h3f, const float* __restrict__ h3b,
    float* __restrict__ out) {
  __shared__ unsigned short A[32 * LDA];
  const int tid = threadIdx.x;
  const int wave = tid >> 6, lane = tid & 63;
  const int lrow = lane & 15, kgrp = lane >> 4;
  const int tile = blockIdx.x * 32;

  {
    const int r = tid >> 4, s = tid & 15;
    const uint4* pg = (const uint4*)(Gb + (size_t)(tile + r) * 384);
#pragma unroll
    for (int i = 0; i < 3; ++i)
      *(uint4*)(&A[r * LDA + (s + 16 * i) * 8]) = pg[s + 16 * i];
  }
  __syncthreads();

  const int jcnt1 = (wave < 4) ? 2 : 1;
  const int jb1 = (wave < 4) ? (wave * 2) : (4 + wave);
  f32x4 acc[2][2];
#pragma unroll
  for (int a = 0; a < 2; ++a)
#pragma unroll
    for (int eb = 0; eb < 2; ++eb)
#pragma unroll
      for (int q = 0; q < 4; ++q) acc[a][eb][q] = 0.f;
#pragma unroll 2
  for (int kk = 0; kk < 12; ++kk) {
    const int k0 = kk * 32 + kgrp * 8;
    bfrag bF[2];
#pragma unroll
    for (int eb = 0; eb < 2; ++eb)
      bF[eb] = *(const bfrag*)(&A[(eb * 16 + lrow) * LDA + k0]);
#pragma unroll
    for (int a = 0; a < 2; ++a) {
      if (a < jcnt1) {
        const bfrag aF = *(const bfrag*)(h1f + ((size_t)((jb1 + a) * 12 + kk) * 64 + lane) * 8);
#pragma unroll
        for (int eb = 0; eb < 2; ++eb)
          acc[a][eb] = __builtin_amdgcn_mfma_f32_16x16x32_bf16(aF, bF[eb], acc[a][eb], 0, 0, 0);
      }
    }
  }
  __syncthreads();
#pragma unroll
  for (int a = 0; a < 2; ++a) {
    if (a < jcnt1) {
      const int j0 = (jb1 + a) * 16 + kgrp * 4;
      const float4 b4 = *(const float4*)(h1b + j0);
#pragma unroll
      for (int eb = 0; eb < 2; ++eb) {
        const int g = eb * 16 + lrow;
        bf16x4 v;
        v[0] = (__bf16)gelu(acc[a][eb][0] + b4.x);
        v[1] = (__bf16)gelu(acc[a][eb][1] + b4.y);
        v[2] = (__bf16)gelu(acc[a][eb][2] + b4.z);
        v[3] = (__bf16)gelu(acc[a][eb][3] + b4.w);
        *(bf16x4*)(&A[g * LDA + j0]) = v;
      }
    }
  }
  __syncthreads();

  f32x4 acc2[2];
#pragma unroll
  for (int eb = 0; eb < 2; ++eb)
#pragma unroll
    for (int q = 0; q < 4; ++q) acc2[eb][q] = 0.f;
  if (wave < 6) {
#pragma unroll 2
    for (int kk = 0; kk < 6; ++kk) {
      const int k0 = kk * 32 + kgrp * 8;
      bfrag bF[2];
#pragma unroll
      for (int eb = 0; eb < 2; ++eb)
        bF[eb] = *(const bfrag*)(&A[(eb * 16 + lrow) * LDA + k0]);
      const bfrag aF = *(const bfrag*)(h2f + ((size_t)(wave * 6 + kk) * 64 + lane) * 8);
#pragma unroll
      for (int eb = 0; eb < 2; ++eb)
        acc2[eb] = __builtin_amdgcn_mfma_f32_16x16x32_bf16(aF, bF[eb], acc2[eb], 0, 0, 0);
    }
  }
  __syncthreads();
  if (wave < 6) {
    const int j0 = wave * 16 + kgrp * 4;
    const float4 b4 = *(const float4*)(h2b + j0);
#pragma unroll
    for (int eb = 0; eb < 2; ++eb) {
      const int g = eb * 16 + lrow;
      bf16x4 v;
      v[0] = (__bf16)gelu(acc2[eb][0] + b4.x);
      v[1] = (__bf16)gelu(acc2[eb][1] + b4.y);
      v[2] = (__bf16)gelu(acc2[eb][2] + b4.z);
      v[3] = (__bf16)gelu(acc2[eb][3] + b4.w);
      *(bf16x4*)(&A[g * LDA + 192 + j0]) = v;
    }
  }
  __syncthreads();

  const int jcnt3 = (wave < 5) ? 2 : 1;
  const int jb3 = (wave < 5) ? (wave * 2) : (wave + 5);
  f32x4 acc3[2][2];
#pragma unroll
  for (int a = 0; a < 2; ++a)
#pragma unroll
    for (int eb = 0; eb < 2; ++eb)
#pragma unroll
      for (int q = 0; q < 4; ++q) acc3[a][eb][q] = 0.f;
#pragma unroll
  for (int kk = 0; kk < 3; ++kk) {
    const int k0 = 192 + kk * 32 + kgrp * 8;
    bfrag bF[2];
#pragma unroll
    for (int eb = 0; eb < 2; ++eb)
      bF[eb] = *(const bfrag*)(&A[(eb * 16 + lrow) * LDA + k0]);
#pragma unroll
    for (int a = 0; a < 2; ++a) {
      if (a < jcnt3) {
        const bfrag aF = *(const bfrag*)(h3f + ((size_t)((jb3 + a) * 3 + kk) * 64 + lane) * 8);
#pragma unroll
        for (int eb = 0; eb < 2; ++eb)
          acc3[a][eb] = __builtin_amdgcn_mfma_f32_16x16x32_bf16(aF, bF[eb], acc3[a][eb], 0, 0, 0);
      }
    }
  }
#pragma unroll
  for (int a = 0; a < 2; ++a) {
    if (a < jcnt3) {
      const int jb = jb3 + a;
      const int j0 = jb * 16 + kgrp * 4;
#pragma unroll
      for (int eb = 0; eb < 2; ++eb) {
        const int g = tile + eb * 16 + lrow;
        if (jb < 12) {
          const float4 b4 = *(const float4*)(h3b + j0);
          float4 o;
          o.x = acc3[a][eb][0] + b4.x;
          o.y = acc3[a][eb][1] + b4.y;
          o.z = acc3[a][eb][2] + b4.z;
          o.w = acc3[a][eb][3] + b4.w;
          *(float4*)(out + (size_t)g * ND + j0) = o;
        } else {
#pragma unroll
          for (int t = 0; t < 4; ++t) {
            const int j = j0 + t;
            if (j < ND) out[(size_t)g * ND + j] = acc3[a][eb][t] + h3b[j];
          }
        }
      }
    }
  }
}

extern "C" void kernel_launch(void* const* d_in, const int* in_sizes, int n_in,
                              void* d_out, int out_size, void* d_ws, size_t ws_size,
                              hipStream_t stream) {
  const float* atom   = (const float*)d_in[0];
  const float* ea     = (const float*)d_in[1];
  const int*   ei     = (const int*)d_in[2];
  const int*   batch  = (const int*)d_in[3];
  const float* enc_w  = (const float*)d_in[4];
  const float* enc_b  = (const float*)d_in[5];
  const float* enc_lng= (const float*)d_in[6];
  const float* enc_lnb= (const float*)d_in[7];
  const float* msg_w1 = (const float*)d_in[8];
  const float* msg_b1 = (const float*)d_in[9];
  const float* msg_w2 = (const float*)d_in[10];
  const float* msg_b2 = (const float*)d_in[11];
  const float* upd_w  = (const float*)d_in[12];
  const float* upd_b  = (const float*)d_in[13];
  const float* ln_g   = (const float*)d_in[14];
  const float* ln_b   = (const float*)d_in[15];
  const float* h1_w   = (const float*)d_in[16];
  const float* h1_b   = (const float*)d_in[17];
  const float* h2_w   = (const float*)d_in[18];
  const float* h2_b   = (const float*)d_in[19];
  const float* h3_w   = (const float*)d_in[20];
  const float* h3_b   = (const float*)d_in[21];
  float* out = (float*)d_out;

  char* ws = (char*)d_ws;
  size_t off = 0;
  auto alloc = [&](size_t bytes) -> void* {
    void* p = ws + off;
    off = (off + bytes + 255) & ~(size_t)255;
    return p;
  };
  __bf16* xb          = (__bf16*)alloc((size_t)NN * H * 2);
  unsigned short* msg = (unsigned short*)alloc((size_t)NE * H * 2);
  unsigned short* W1f = (unsigned short*)alloc((size_t)NL * 147456 * 2);
  float* w1last       = (float*)alloc((size_t)NL * 384 * 4);
  unsigned short* W2f = (unsigned short*)alloc((size_t)NL * 73728 * 2);
  unsigned short* Uxf = (unsigned short*)alloc((size_t)NL * 36864 * 2);
  float* W2p          = (float*)alloc((size_t)NL * 384 * 192 * 4);
  float* v2           = (float*)alloc((size_t)NL * 192 * 4);
  unsigned short* h1f = (unsigned short*)alloc((size_t)73728 * 2);
  unsigned short* h2f = (unsigned short*)alloc((size_t)18432 * 2);
  unsigned short* h3f = (unsigned short*)alloc((size_t)19968 * 2);
  __bf16* Gb          = (__bf16*)alloc((size_t)NG * 384 * 2);
  int* deg            = (int*)alloc((size_t)NN * 4);
  int* cstart         = (int*)alloc((size_t)(NN + 1) * 4);
  int* pos            = (int*)alloc((size_t)NE * 4);
  int* gstart         = (int*)alloc((size_t)NG * 4);
  int* gend           = (int*)alloc((size_t)NG * 4);

  fold_kernel<<<NL * 97, 256, 0, stream>>>(msg_w2, upd_w, msg_b2, W2p, v2);
  prep_kernel<<<5486, 256, 0, stream>>>(msg_w1, W2p, upd_w, h1_w, h2_w, h3_w,
                                        W1f, w1last, W2f, Uxf, h1f, h2f, h3f);
  enc_kernel<<<NN / 4, 256, 0, stream>>>(atom, enc_w, enc_b, enc_lng, enc_lnb, xb);

  hipMemsetAsync(deg, 0, (size_t)NN * 4, stream);
  csr_count<<<(NE + 255) / 256, 256, 0, stream>>>(ei, deg);
  csr_scan<<<1, 1024, 0, stream>>>(deg, cstart);
  hipMemsetAsync(deg, 0, (size_t)NN * 4, stream);
  csr_fill<<<(NE + 255) / 256, 256, 0, stream>>>(ei, cstart, deg, pos);

  hipMemsetAsync(gstart, 0, (size_t)NG * 4, stream);
  hipMemsetAsync(gend, 0, (size_t)NG * 4, stream);
  gseg_kernel<<<(NN + 255) / 256, 256, 0, stream>>>(batch, gstart, gend);

  for (int l = 0; l < NL; ++l) {
    msg_kernel<<<NE / 64, 512, 0, stream>>>(
        xb, ei, ea, pos, W1f + (size_t)l * 147456, w1last + l * 384,
        msg_b1 + l * 384, W2f + (size_t)l * 73728, msg);
    upd_kernel<<<(NN + NT - 1) / NT, 512, 0, stream>>>(
        Uxf + (size_t)l * 36864, upd_b + l * 192, v2 + l * 192,
        ln_g + l * 192, ln_b + l * 192, msg, cstart, xb);
  }
  pool_kernel<<<NG / 4, 256, 0, stream>>>(xb, gstart, gend, Gb);
  head_kernel<<<NG / 32, 512, 0, stream>>>(Gb, h1f, h1_b, h2f, h2_b, h3f, h3_b, out);
}